// Round 17
// baseline (138.546 us; speedup 1.0000x reference)
//
#include <hip/hip_runtime.h>

typedef _Float16 f16;
typedef f16   f16x8 __attribute__((ext_vector_type(8)));
typedef float f32x4 __attribute__((ext_vector_type(4)));
typedef __attribute__((address_space(3))) char as3char;

#define MFMA16(a, b, c) __builtin_amdgcn_mfma_f32_16x16x32_f16((a), (b), (c), 0, 0, 0)

// ---- weight image: linear granule sequence S[i] at i*4096 f16 (8 KB each) ----
// S0-7:  w1 (kq*2+nh), natural k
// S8-9:  w2 kh0, kh1 (sigma k)
// S10-25: experts e0..e3, per e: {ew1h0, ew2h0, ew1h1, ew2h1} (sigma)
// S26:   sw (sigma)
// S27:   hw1[0] | hw1[1] (2048+2048, sigma)
// S28:   hw1[2] (2048, sigma; rest unused)
// gw1 at 118784 (2048 f16, sigma) - staged once into G
#define IMG_GW1  118784

__device__ __forceinline__ float silu_f(float v) {
    return v * __builtin_amdgcn_rcpf(1.0f + __expf(-v));
}

// sigma: D-frag register order -> k feature. s = 32ks + 8q + i.
__device__ __forceinline__ int sigma_k(int s) {
    const int ks = s >> 5, qq = (s >> 3) & 3, i = s & 7;
    return 16 * (2 * ks + (i >> 2)) + 4 * qq + (i & 3);
}

// ============ prep: fp32 src[K][N] block -> f16 granule [n][slot ^ ((n&7)<<3)] ============
template<bool SIG>
__device__ void conv_blk(const float* __restrict__ src, f16* __restrict__ dst,
                         int srcN, int k0, int n0, int KB, int NB, int tid, int nth) {
    for (int idx = tid; idx < KB * NB; idx += nth) {
        const int s = idx / NB, nn = idx - s * NB;      // s = logical k-slot
        const int k = SIG ? sigma_k(s) : s;
        dst[nn * KB + (s ^ ((nn & 7) << 3))] = (f16)src[(long)(k0 + k) * srcN + n0 + nn];
    }
}

__global__ void prep_weights(const float* __restrict__ w1, const float* __restrict__ w2,
                             const float* __restrict__ gw1, const float* __restrict__ ew1,
                             const float* __restrict__ ew2, const float* __restrict__ sw,
                             const float* __restrict__ hw1, f16* __restrict__ ws) {
    const int tid = blockIdx.x * 256 + threadIdx.x;
    const int nth = gridDim.x * 256;
    for (int kq = 0; kq < 4; ++kq)
        for (int nh = 0; nh < 2; ++nh)
            conv_blk<false>(w1, ws + (kq * 2 + nh) * 4096, 128, kq * 64, nh * 64, 64, 64, tid, nth);
    for (int kh = 0; kh < 2; ++kh)
        conv_blk<true>(w2, ws + (8 + kh) * 4096, 64, kh * 64, 0, 64, 64, tid, nth);
    for (int e = 0; e < 4; ++e)
        for (int h = 0; h < 2; ++h) {
            conv_blk<true>(ew1 + e * 8192, ws + (10 + e * 4 + h * 2) * 4096,     128, 0, h * 64, 64, 64, tid, nth);
            conv_blk<true>(ew2 + e * 8192, ws + (10 + e * 4 + h * 2 + 1) * 4096,  64, h * 64, 0, 64, 64, tid, nth);
        }
    conv_blk<true>(sw, ws + 26 * 4096, 64, 0, 0, 64, 64, tid, nth);
    for (int h = 0; h < 2; ++h)
        conv_blk<true>(hw1 + h * 2048, ws + 27 * 4096 + h * 2048, 32, 0, 0, 64, 32, tid, nth);
    conv_blk<true>(hw1 + 2 * 2048, ws + 28 * 4096, 32, 0, 0, 64, 32, tid, nth);
    conv_blk<true>(gw1, ws + IMG_GW1, 32, 0, 0, 64, 32, tid, nth);
}

// ============ async global->LDS staging: 1KB chunks round-robined over 4 waves ============
template<int BYTES>
__device__ __forceinline__ void stage4(const f16* __restrict__ g, as3char* l, int wv, int lane) {
    constexpr int CH = BYTES / 1024;
    #pragma unroll
    for (int ch = 0; ch < CH; ++ch)
        if ((ch & 3) == wv)
            __builtin_amdgcn_global_load_lds(
                (const __attribute__((address_space(1))) void*)((const char*)g + ch * 1024 + lane * 16),
                (__attribute__((address_space(3))) void*)(l + ch * 1024), 16, 0, 0);
}
#define STG(i, dst) stage4<8192>(wsp + (i) * 4096, dst, wv, lane)

// ============ weight A-frag from swizzled LDS granule ============
__device__ __forceinline__ int swzW(int n) { return (n & 7) << 3; }

__device__ __forceinline__ f16x8 ldW(const f16* base, int row_base, int k0, int lane) {
    const int r = row_base + (lane & 15);
    const int k = k0 + ((lane >> 4) << 3);
    return *(const f16x8*)(base + r * 64 + (k ^ swzW(r)));
}

// NT n-tiles: acc[n] += W(A) x act(B)
template<int NT>
__device__ __forceinline__ void mmN(const f16x8 bf[2], const f16* wb, f32x4* acc, int lane) {
    #pragma unroll
    for (int ks = 0; ks < 2; ++ks)
        #pragma unroll
        for (int n = 0; n < NT; ++n) {
            const f16x8 w = ldW(wb, n * 16, ks * 32, lane);
            acc[n] = MFMA16(w, bf[ks], acc[n]);
        }
}

// D-acc (4 tiles) -> B-frags, register-only (order matches sigma)
__device__ __forceinline__ void silu_pack(const f32x4* a4, f16x8 bf[2]) {
    #pragma unroll
    for (int ks = 0; ks < 2; ++ks)
        #pragma unroll
        for (int i = 0; i < 8; ++i)
            bf[ks][i] = (f16)silu_f(a4[2 * ks + (i >> 2)][i & 3]);
}
__device__ __forceinline__ void pack_raw(const f32x4* a4, f16x8 bf[2]) {
    #pragma unroll
    for (int ks = 0; ks < 2; ++ks)
        #pragma unroll
        for (int i = 0; i < 8; ++i)
            bf[ks][i] = (f16)a4[2 * ks + (i >> 2)][i & 3];
}

__device__ __forceinline__ f16x8 cvt8(float4 a, float4 b) {
    f16x8 r;
    r[0] = (f16)a.x; r[1] = (f16)a.y; r[2] = (f16)a.z; r[3] = (f16)a.w;
    r[4] = (f16)b.x; r[5] = (f16)b.y; r[6] = (f16)b.z; r[7] = (f16)b.w;
    return r;
}

// sum across the 4 quad lanes {j, j+16, j+32, j+48}
__device__ __forceinline__ float qreduce(float v) {
    v += __shfl_xor(v, 16, 64);
    v += __shfl_xor(v, 32, 64);
    return v;
}

__global__ __launch_bounds__(256, 5)
void fused_net_mfma(const float* __restrict__ x,   const f16* __restrict__ wsp,
                    const float* __restrict__ b1,  const float* __restrict__ lng,
                    const float* __restrict__ lnb, const float* __restrict__ b2,
                    const float* __restrict__ eb1, const float* __restrict__ eb2,
                    const float* __restrict__ gb1, const float* __restrict__ gw2,
                    const float* __restrict__ gb2, const float* __restrict__ sb,
                    const float* __restrict__ hb1, const float* __restrict__ hw2,
                    const float* __restrict__ hb2, float* __restrict__ out)
{
    // 28 KB LDS: B0/B1/B2 8K each (3-deep rotation) | G 4K. 5 blocks/CU.
    // Phase p computes from B[p%3]; stage of S[p+2] was issued at phase p
    // targeting B[(p+2)%3] -> every load gets ~2 phases to land.
    __shared__ __align__(16) f16 lds[14336];
    as3char* const LB = (as3char*)lds;
    const int lane = threadIdx.x & 63;
    const int wv   = threadIdx.x >> 6;
    const int j    = lane & 15;
    const int q    = lane >> 4;
    const int q4   = q * 4;
    f16* const B0 = lds;          as3char* const B0_3 = LB;
    f16* const B1 = lds + 4096;   as3char* const B1_3 = LB + 8192;
    f16* const B2 = lds + 8192;   as3char* const B2_3 = LB + 16384;
    f16* const G  = lds + 12288;  as3char* const G_3  = LB + 24576;

    const long row0 = (long)blockIdx.x * 64 + wv * 16;
    const float* xrow = x + (row0 + j) * 256 + q * 8;

    // ---- prologue: S0->B0, S1->B1, gw1->G; x quarter 0 -> regs ----
    STG(0, B0_3);
    STG(1, B1_3);
    stage4<4096>(wsp + IMG_GW1, G_3, wv, lane);
    float4 xr[4];
    xr[0] = *(const float4*)(xrow);      xr[1] = *(const float4*)(xrow + 4);
    xr[2] = *(const float4*)(xrow + 32); xr[3] = *(const float4*)(xrow + 36);
    __syncthreads();

    // ================= stem1: phases 0..7 (S0..S7 = w1) =================
    f32x4 acc[8];
    #pragma unroll
    for (int t = 0; t < 8; ++t)
        acc[t] = *(const f32x4*)(b1 + t * 16 + q4);

    // phase macro for stem1: cur buffer, stage idx -> stage buffer, acc offset, next-x quarter (or -1)
    #define STEM1_PH(CUR, SIDX, SBUF, AOFS, NXTQ)                                   \
    {                                                                                \
        STG(SIDX, SBUF);                                                             \
        f16x8 af[2];                                                                 \
        af[0] = cvt8(xr[0], xr[1]);                                                  \
        af[1] = cvt8(xr[2], xr[3]);                                                  \
        if (NXTQ >= 0) {                                                             \
            const float* xb = xrow + (NXTQ) * 64;                                    \
            xr[0] = *(const float4*)(xb);      xr[1] = *(const float4*)(xb + 4);     \
            xr[2] = *(const float4*)(xb + 32); xr[3] = *(const float4*)(xb + 36);    \
        }                                                                            \
        mmN<4>(af, CUR, acc + (AOFS), lane);                                         \
        __syncthreads();                                                             \
    }
    STEM1_PH(B0, 2, B2_3, 0, -1);   // ph0: w1 kq0 nh0
    STEM1_PH(B1, 3, B0_3, 4,  1);   // ph1: w1 kq0 nh1, prefetch x q1
    STEM1_PH(B2, 4, B1_3, 0, -1);   // ph2: kq1 nh0
    STEM1_PH(B0, 5, B2_3, 4,  2);   // ph3: kq1 nh1, x q2
    STEM1_PH(B1, 6, B0_3, 0, -1);   // ph4: kq2 nh0
    STEM1_PH(B2, 7, B1_3, 4,  3);   // ph5: kq2 nh1, x q3
    STEM1_PH(B0, 8, B2_3, 0, -1);   // ph6: kq3 nh0
    STEM1_PH(B1, 9, B0_3, 4, -1);   // ph7: kq3 nh1
    #undef STEM1_PH

    // ---- LN stats ----
    float s = 0.f, ss = 0.f;
    #pragma unroll
    for (int t = 0; t < 8; ++t)
        #pragma unroll
        for (int g = 0; g < 4; ++g) { const float v = acc[t][g]; s += v; ss += v * v; }
    s = qreduce(s); ss = qreduce(ss);
    const float mu  = s * 0.0078125f;
    const float rsv = rsqrtf(ss * 0.0078125f - mu * mu + 1e-5f);

    // ================= ph8 (B2 = w2 kh0): stage S10 -> B1 =================
    f32x4 a2[4];
    #pragma unroll
    for (int t = 0; t < 4; ++t)
        a2[t] = *(const f32x4*)(b2 + t * 16 + q4);
    STG(10, B1_3);
    {
        f16x8 bf[2];
        #pragma unroll
        for (int ks = 0; ks < 2; ++ks)
            #pragma unroll
            for (int u = 0; u < 2; ++u) {
                const int t = 2 * ks + u;
                const f32x4 g4  = *(const f32x4*)(lng + 16 * t + q4);
                const f32x4 bb4 = *(const f32x4*)(lnb + 16 * t + q4);
                #pragma unroll
                for (int g = 0; g < 4; ++g)
                    bf[ks][4 * u + g] = (f16)silu_f((acc[t][g] - mu) * rsv * g4[g] + bb4[g]);
            }
        mmN<4>(bf, B2, a2, lane);
    }
    __syncthreads();

    // ================= ph9 (B0 = w2 kh1): stage S11 -> B2; gate =================
    STG(11, B2_3);
    f16x8 hbB[2];
    f32x4 gwt;
    {
        f16x8 bf[2];
        #pragma unroll
        for (int ks = 0; ks < 2; ++ks)
            #pragma unroll
            for (int u = 0; u < 2; ++u) {
                const int t = 4 + 2 * ks + u;
                const f32x4 g4  = *(const f32x4*)(lng + 16 * t + q4);
                const f32x4 bb4 = *(const f32x4*)(lnb + 16 * t + q4);
                #pragma unroll
                for (int g = 0; g < 4; ++g)
                    bf[ks][4 * u + g] = (f16)silu_f((acc[t][g] - mu) * rsv * g4[g] + bb4[g]);
            }
        mmN<4>(bf, B0, a2, lane);
        silu_pack(a2, hbB);

        f32x4 ag[2];
        #pragma unroll
        for (int t = 0; t < 2; ++t)
            ag[t] = *(const f32x4*)(gb1 + t * 16 + q4);
        mmN<2>(hbB, G, ag, lane);
        f32x4 pg = {0, 0, 0, 0};
        #pragma unroll
        for (int t = 0; t < 2; ++t)
            #pragma unroll
            for (int g = 0; g < 4; ++g) {
                const int f = 16 * t + q4 + g;
                const f32x4 w4 = *(const f32x4*)(gw2 + f * 4);
                pg += silu_f(ag[t][g]) * w4;
            }
        #pragma unroll
        for (int o = 0; o < 4; ++o) pg[o] = qreduce(pg[o]);
        const f32x4 l = pg + *(const f32x4*)gb2;
        const float mx = fmaxf(fmaxf(l[0], l[1]), fmaxf(l[2], l[3]));
        f32x4 ee;
        #pragma unroll
        for (int o = 0; o < 4; ++o) ee[o] = __expf(l[o] - mx);
        gwt = ee * __builtin_amdgcn_rcpf(ee[0] + ee[1] + ee[2] + ee[3]);
    }
    __syncthreads();

    // ================= experts: phases 10..25, fully unrolled =================
    f32x4 moe[4] = {{0,0,0,0},{0,0,0,0},{0,0,0,0},{0,0,0,0}};
    // per-expert phase quartet: compute bufs CA..CD, stage dests SA..SD (sources S[10+4e+2..+5])
    #define EXPERT(E, CA, SA, CB, SB, CC, SC, CD, SD)                                \
    {                                                                                \
        f32x4 a2e[4];                                                                \
        _Pragma("unroll")                                                            \
        for (int t = 0; t < 4; ++t)                                                  \
            a2e[t] = *(const f32x4*)(eb2 + (E) * 64 + t * 16 + q4);                  \
        f16x8 eaB[2];                                                                \
        STG(10 + 4 * (E) + 2, SA);                                                   \
        {                                                                            \
            f32x4 aa[4];                                                             \
            _Pragma("unroll")                                                        \
            for (int t = 0; t < 4; ++t)                                              \
                aa[t] = *(const f32x4*)(eb1 + (E) * 128 + t * 16 + q4);              \
            mmN<4>(hbB, CA, aa, lane);                                               \
            silu_pack(aa, eaB);                                                      \
        }                                                                            \
        __syncthreads();                                                             \
        STG(10 + 4 * (E) + 3, SB);                                                   \
        mmN<4>(eaB, CB, a2e, lane);                                                  \
        __syncthreads();                                                             \
        STG(10 + 4 * (E) + 4, SC);                                                   \
        {                                                                            \
            f32x4 aa[4];                                                             \
            _Pragma("unroll")                                                        \
            for (int t = 0; t < 4; ++t)                                              \
                aa[t] = *(const f32x4*)(eb1 + (E) * 128 + 64 + t * 16 + q4);         \
            mmN<4>(hbB, CC, aa, lane);                                               \
            silu_pack(aa, eaB);                                                      \
        }                                                                            \
        __syncthreads();                                                             \
        STG(10 + 4 * (E) + 5, SD);                                                   \
        mmN<4>(eaB, CD, a2e, lane);                                                  \
        {                                                                            \
            const float ge = gwt[E];                                                 \
            _Pragma("unroll")                                                        \
            for (int t = 0; t < 4; ++t)                                              \
                _Pragma("unroll")                                                    \
                for (int g = 0; g < 4; ++g)                                          \
                    moe[t][g] += silu_f(a2e[t][g]) * ge;                             \
        }                                                                            \
        __syncthreads();                                                             \
    }
    EXPERT(0, B1, B0_3, B2, B1_3, B0, B2_3, B1, B0_3);   // ph10-13
    EXPERT(1, B2, B1_3, B0, B2_3, B1, B0_3, B2, B1_3);   // ph14-17
    EXPERT(2, B0, B2_3, B1, B0_3, B2, B1_3, B0, B2_3);   // ph18-21
    EXPERT(3, B1, B0_3, B2, B1_3, B0, B2_3, B1, B0_3);   // ph22-25
    #undef EXPERT

    // ================= ph26 (B2 = sw): stage S28 -> B1; feat =================
    STG(28, B1_3);
    f16x8 featB[2];
    {
        f16x8 moeB[2];
        pack_raw(moe, moeB);
        f32x4 fs[4];
        #pragma unroll
        for (int t = 0; t < 4; ++t)
            fs[t] = *(const f32x4*)(sb + t * 16 + q4);
        mmN<4>(moeB, B2, fs, lane);
        silu_pack(fs, featB);
    }
    __syncthreads();   // hw1[0,1] in B0 (S27, staged ph25), hw1[2] in B1 (S28)

    // ================= heads: hw1[0]=B0, hw1[1]=B0+2048, hw1[2]=B1 ================
    #pragma unroll
    for (int h = 0; h < 3; ++h) {
        const f16* hw = (h == 0) ? B0 : (h == 1) ? (B0 + 2048) : B1;
        f32x4 ah[2];
        #pragma unroll
        for (int t = 0; t < 2; ++t)
            ah[t] = *(const f32x4*)(hb1 + h * 32 + t * 16 + q4);
        mmN<2>(featB, hw, ah, lane);
        float ph = 0.f;
        #pragma unroll
        for (int t = 0; t < 2; ++t) {
            const f32x4 w4 = *(const f32x4*)(hw2 + h * 32 + t * 16 + q4);
            #pragma unroll
            for (int g = 0; g < 4; ++g)
                ph += silu_f(ah[t][g]) * w4[g];
        }
        ph = qreduce(ph);
        if (q == h) out[(row0 + j) * 3 + h] = ph + hb2[h];
    }
}

extern "C" void kernel_launch(void* const* d_in, const int* in_sizes, int n_in,
                              void* d_out, int out_size, void* d_ws, size_t ws_size,
                              hipStream_t stream) {
    const float* x    = (const float*)d_in[0];
    const float* w1   = (const float*)d_in[1];
    const float* b1   = (const float*)d_in[2];
    const float* lng  = (const float*)d_in[3];
    const float* lnb  = (const float*)d_in[4];
    const float* w2   = (const float*)d_in[5];
    const float* b2   = (const float*)d_in[6];
    const float* ew1  = (const float*)d_in[7];
    const float* eb1  = (const float*)d_in[8];
    const float* ew2  = (const float*)d_in[9];
    const float* eb2  = (const float*)d_in[10];
    const float* gw1  = (const float*)d_in[11];
    const float* gb1  = (const float*)d_in[12];
    const float* gw2  = (const float*)d_in[13];
    const float* gb2  = (const float*)d_in[14];
    const float* sw   = (const float*)d_in[15];
    const float* sb   = (const float*)d_in[16];
    const float* hw1  = (const float*)d_in[17];
    const float* hb1  = (const float*)d_in[18];
    const float* hw2  = (const float*)d_in[19];
    const float* hb2  = (const float*)d_in[20];
    float* out = (float*)d_out;
    f16* ws = (f16*)d_ws;

    hipLaunchKernelGGL(prep_weights, dim3(64), dim3(256), 0, stream,
                       w1, w2, gw1, ew1, ew2, sw, hw1, ws);

    const int B = in_sizes[0] / 256;
    const int grid = B / 64;
    hipLaunchKernelGGL(fused_net_mfma, dim3(grid), dim3(256), 0, stream,
                       x, ws, b1, lng, lnb, b2, eb1, eb2, gb1, gw2, gb2,
                       sb, hb1, hw2, hb2, out);
}